// Round 7
// baseline (281.956 us; speedup 1.0000x reference)
//
#include <hip/hip_runtime.h>
#include <math.h>

// AxialAttention on MI355X — round 6.
// K1/prep unchanged (residual ~130us confirmed fixed overhead + ~30us K1).
// K2 occupancy round: s16 (p-plane) aliased onto s32 (raw scores) via
// two-pass Phase C -> LDS 24->17.3 KB -> 8 blocks/CU; launch_bounds(256,8);
// pointer-bumped global addressing in B/D loops.

typedef _Float16 f16;
typedef _Float16 f16x2 __attribute__((ext_vector_type(2)));
typedef _Float16 f16x4 __attribute__((ext_vector_type(4)));
typedef _Float16 f16x8 __attribute__((ext_vector_type(8)));
typedef float    f32x4 __attribute__((ext_vector_type(4)));
typedef unsigned int u32;
typedef unsigned int u32x2 __attribute__((ext_vector_type(2)));

static constexpr int NB    = 32;
static constexpr int HH    = 56;
static constexpr int CIN   = 128;
static constexpr int GG    = 8;
static constexpr int PLANE = HH * HH;     // 3136
static constexpr int MT    = 112;         // K1 M-tile (2 j-rows x 56 w)
static constexpr int NBLK  = 28;          // 3136 / 112

// -------------------------------------------------------------------------
// prep: Wt[d][k] f16, d in [0,256): 0-63 <- wq, 64-127 <- wk, 128-255 <- wv
// -------------------------------------------------------------------------
__global__ __launch_bounds__(256) void prep_kernel(
    const float* __restrict__ wq, const float* __restrict__ wk,
    const float* __restrict__ wv, f16* __restrict__ wt)
{
    const int id = blockIdx.x * 256 + threadIdx.x;   // 4096 total
    const int d = id >> 4, kc = id & 15;
    const float* src; int stride, dl;
    if (d < 64)       { src = wq; stride = 64;  dl = d; }
    else if (d < 128) { src = wk; stride = 64;  dl = d - 64; }
    else              { src = wv; stride = 128; dl = d - 128; }
    f16x8 v;
    #pragma unroll
    for (int kk = 0; kk < 8; ++kk)
        v[kk] = (f16)src[(kc * 8 + kk) * stride + dl];
    *(f16x8*)&wt[d * 128 + kc * 8] = v;
}

// -------------------------------------------------------------------------
// K1: block tile 112(M) x 128(N), K=128. Grid (896, 2): y=0 -> q|k, y=1 -> v.
// -------------------------------------------------------------------------
__global__ __launch_bounds__(256, 2) void qkv_kernel(
    const float* __restrict__ x, const f16* __restrict__ wt,
    const float* __restrict__ gq, const float* __restrict__ bq,
    const float* __restrict__ gk, const float* __restrict__ bk,
    const float* __restrict__ gv, const float* __restrict__ bv,
    f16* __restrict__ qt, f16* __restrict__ kt, f16* __restrict__ vt2)
{
    __shared__ f16 lds_a[MT * 136];     // A[m][k], later reused as C[m][d]
    __shared__ f16 lds_b[128 * 136];    // Bt[n][k]

    const int t    = threadIdx.x;
    const int nh   = blockIdx.y;
    const int b    = blockIdx.x / NBLK;
    const int B28  = blockIdx.x - b * NBLK;
    const int rem0 = B28 * MT;
    const size_t m0 = (size_t)b * PLANE + rem0;

    // ---- stage A: 112x128 f32 -> f16, coalesced float4 ----
    {
        const float4* xs = (const float4*)(x + m0 * CIN);
        #pragma unroll
        for (int it = 0; it < 14; ++it) {
            const int f = it * 256 + t;          // 3584 float4
            const int r = f >> 5, c = f & 31;
            const float4 v = xs[f];
            f16x4 p; p.x = (f16)v.x; p.y = (f16)v.y; p.z = (f16)v.z; p.w = (f16)v.w;
            *(f16x4*)&lds_a[r * 136 + c * 4] = p;
        }
    }
    // ---- stage B: pre-converted Wt, coalesced 16B ----
    #pragma unroll
    for (int it = 0; it < 8; ++it) {
        const int f = it * 256 + t;              // 2048 chunks
        const int n = f >> 4, kc = f & 15;
        *(f16x8*)&lds_b[n * 136 + kc * 8] =
            *(const f16x8*)&wt[(size_t)(nh * 128 + n) * 128 + kc * 8];
    }
    __syncthreads();

    const int lane = t & 63, wid = t >> 6;
    const int wn0 = wid * 32;
    const int ra = lane & 15, qd = lane >> 4;

    f32x4 acc[7][2];
    #pragma unroll
    for (int mt = 0; mt < 7; ++mt)
        #pragma unroll
        for (int nt = 0; nt < 2; ++nt)
            acc[mt][nt] = (f32x4){0.f, 0.f, 0.f, 0.f};

    #pragma unroll
    for (int ks = 0; ks < 4; ++ks) {
        f16x8 af[7], bf[2];
        #pragma unroll
        for (int mt = 0; mt < 7; ++mt)
            af[mt] = *(const f16x8*)&lds_a[(mt * 16 + ra) * 136 + ks * 32 + qd * 8];
        #pragma unroll
        for (int nt = 0; nt < 2; ++nt)
            bf[nt] = *(const f16x8*)&lds_b[(wn0 + nt * 16 + ra) * 136 + ks * 32 + qd * 8];
        #pragma unroll
        for (int mt = 0; mt < 7; ++mt)
            #pragma unroll
            for (int nt = 0; nt < 2; ++nt)
                acc[mt][nt] = __builtin_amdgcn_mfma_f32_16x16x32_f16(
                    af[mt], bf[nt], acc[mt][nt], 0, 0, 0);
    }
    __syncthreads();

    // ---- BN + f16, transpose via LDS (reuse lds_a as C[m][d]) ----
    f16* lds_c = lds_a;
    const float inv = 1.0f / sqrtf(1.001f);
    #pragma unroll
    for (int nt = 0; nt < 2; ++nt) {
        const int d  = wn0 + nt * 16 + ra;       // block-local col 0..127
        const int dg = nh * 128 + d;             // global col 0..255
        float scale, shift;
        if (dg < 64)       { scale = gq[dg] * inv;        shift = bq[dg]; }
        else if (dg < 128) { scale = gk[dg - 64] * inv;   shift = bk[dg - 64]; }
        else               { scale = gv[dg - 128] * inv;  shift = bv[dg - 128]; }
        #pragma unroll
        for (int mt = 0; mt < 7; ++mt)
            #pragma unroll
            for (int rg = 0; rg < 4; ++rg) {
                const int m = mt * 16 + qd * 4 + rg;
                lds_c[m * 136 + d] = (f16)fmaf(acc[mt][nt][rg], scale, shift);
            }
    }
    __syncthreads();

    if (nh == 0) {
        // q/k: 16B row stores, coalesced
        const int rl = t & 31, gs2 = t >> 5;
        #pragma unroll
        for (int it = 0; it < 4; ++it) {
            const int rem = it * 32 + rl;
            if (rem < MT) {
                #pragma unroll
                for (int half = 0; half < 2; ++half) {
                    const int gslot = half * 8 + gs2;
                    const f16x8 v = *(const f16x8*)&lds_c[rem * 136 + gslot * 8];
                    f16* dst = (gslot < 8) ? qt : kt;
                    const int g = gslot & 7;
                    *(f16x8*)&dst[((size_t)(b * GG + g) * PLANE + rem0 + rem) * 8] = v;
                }
            }
        }
    } else {
        // v -> vt2[bg][J=B28][w][c][jbit]: interleave rows w and w+56
        const int cq = t & 3, w8 = (t >> 2) & 7, g = t >> 5;
        #pragma unroll
        for (int it = 0; it < 7; ++it) {
            const int w = it * 8 + w8;
            const int doff = g * 16 + cq * 4;
            const u32x2 a  = *(const u32x2*)&lds_c[w * 136 + doff];         // j0: c0..c3
            const u32x2 bb = *(const u32x2*)&lds_c[(56 + w) * 136 + doff];  // j1: c0..c3
            uint4 o;
            o.x = __builtin_amdgcn_perm(a.x, bb.x, 0x01000504u);  // c0j0 c0j1
            o.y = __builtin_amdgcn_perm(a.x, bb.x, 0x03020706u);  // c1j0 c1j1
            o.z = __builtin_amdgcn_perm(a.y, bb.y, 0x01000504u);  // c2j0 c2j1
            o.w = __builtin_amdgcn_perm(a.y, bb.y, 0x03020706u);  // c3j0 c3j1
            const size_t base =
                (((size_t)(b * GG + g) * NBLK + B28) * HH + w) * 32 + cq * 8;
            *(uint4*)&vt2[base] = o;
        }
    }
}

// -------------------------------------------------------------------------
// K2: one block per (b, i, g). s16 aliases s32 (scores dead after Phase C
// pass 1); LDS ~17.3 KB -> 8 blocks/CU.
// -------------------------------------------------------------------------
__global__ __launch_bounds__(256, 8) void attn_kernel(
    const f16* __restrict__ qt, const f16* __restrict__ kt, const f16* __restrict__ vt2,
    const float* __restrict__ q_rel, const float* __restrict__ k_rel, const float* __restrict__ v_rel,
    const float* __restrict__ g_qk, const float* __restrict__ b_qk,
    const float* __restrict__ g_qr, const float* __restrict__ b_qr,
    const float* __restrict__ g_kr, const float* __restrict__ b_kr,
    const float* __restrict__ g_sv, const float* __restrict__ b_sv,
    const float* __restrict__ g_sve, const float* __restrict__ b_sve,
    float* __restrict__ out)
{
    const int i = blockIdx.x;   // 56
    const int g = blockIdx.y;   // 8
    const int b = blockIdx.z;   // 32
    const int t = threadIdx.x;

    __shared__ __align__(16) char sraw[56 * 57 * 4];  // 12768 B union:
    float (*s32)[57] = (float (*)[57])sraw;           //  raw scores [j][w] f32
    f16* s16 = (f16*)sraw;                            //  then sim [w][j] f16 (56*58)
    __shared__ f16 qi[56 * 8];      // q5[b,i,w,g,:]
    __shared__ f16 qe[56 * 8];      // q_emb[i,j,:] = q_rel[i-j+55]
    __shared__ f16 ke[56 * 8];      // k_emb[j,i,:] = k_rel[j-i+55]
    __shared__ f16 ve2[28 * 32];    // v_emb j-pair-interleaved [J][c][jbit]

    const float inv = 1.0f / sqrtf(1.001f);
    const int bg = (b * GG + g) * PLANE;

    // ---- Phase A: stage LDS ----
    if (t < 56)
        *(f16x8*)&qi[t * 8] = *(const f16x8*)&qt[(size_t)(bg + i * HH + t) * 8];
    for (int idx = t; idx < 448; idx += 256) {
        const int j = idx >> 3, c = idx & 7;
        qe[idx] = (f16)q_rel[(i - j + 55) * 8 + c];
        ke[idx] = (f16)k_rel[(j - i + 55) * 8 + c];
    }
    for (int idx = t; idx < 896; idx += 256) {
        const int J = idx >> 5, r = idx & 31, c = r >> 1, jb = r & 1;
        ve2[idx] = (f16)v_rel[(2 * J + jb - i + 55) * 16 + c];
    }
    const float sqk = g_qk[g] * inv, bqk = b_qk[g];
    const float sqr = g_qr[g] * inv, bqr = b_qr[g];
    const float skr = g_kr[g] * inv, bkr = b_kr[g];
    __syncthreads();

    // ---- Phase B: raw scores; wave = 14 j-rows, lane = w; no cross-lane ----
    {
        const int wv = t >> 6, lane = t & 63;
        const int wc = (lane < 56) ? lane : 55;
        const f16x8 qv = *(const f16x8*)&qi[wc * 8];
        const f16* kp = kt + (size_t)(bg + wv * 14 * HH + wc) * 8;
        const f16* ep = qe + wv * 14 * 8;
        const f16* fp = ke + wv * 14 * 8;
        for (int jj = 0; jj < 14; ++jj) {
            const int j = wv * 14 + jj;
            const f16x8 kv = *(const f16x8*)kp;
            const f16x8 ev = *(const f16x8*)ep;   // LDS broadcast
            const f16x8 fv = *(const f16x8*)fp;   // LDS broadcast
            float qk = 0.f, qr = 0.f, kr = 0.f;
            #pragma unroll
            for (int c = 0; c < 4; ++c) {
                const f16x2 kk = ((const f16x2*)&kv)[c];
                const f16x2 qq = ((const f16x2*)&qv)[c];
                qk = __builtin_amdgcn_fdot2(qq, kk, qk, false);
                qr = __builtin_amdgcn_fdot2(qq, ((const f16x2*)&ev)[c], qr, false);
                kr = __builtin_amdgcn_fdot2(kk, ((const f16x2*)&fv)[c], kr, false);
            }
            const float s = fmaf(sqk, qk, bqk) + fmaf(sqr, qr, bqr) + fmaf(skr, kr, bkr);
            if (lane < 56) s32[j][lane] = s;
            kp += HH * 8;
            ep += 8;
            fp += 8;
        }
    }
    __syncthreads();

    // ---- Phase C: softmax per j-row, two-pass so s16 can alias s32.
    //      t<224: j=t>>2, quarter=t&3 (14 w each); quad-DPP reductions. ----
    float e[14];
    int w0 = 0, cj = 0;
    if (t < 224) {
        cj = t >> 2;
        const int q = t & 3;
        w0 = q * 14;
        const float* row = &s32[cj][w0];
        float mx = row[0];
        #pragma unroll
        for (int wi = 1; wi < 14; ++wi) mx = fmaxf(mx, row[wi]);
        mx = fmaxf(mx, __shfl_xor(mx, 1));
        mx = fmaxf(mx, __shfl_xor(mx, 2));
        float sum = 0.f;
        #pragma unroll
        for (int wi = 0; wi < 14; ++wi) { e[wi] = __expf(row[wi] - mx); sum += e[wi]; }
        sum += __shfl_xor(sum, 1);
        sum += __shfl_xor(sum, 2);
        const float rs = __builtin_amdgcn_rcpf(sum);
        #pragma unroll
        for (int wi = 0; wi < 14; ++wi) e[wi] *= rs;
    }
    __syncthreads();   // all s32 reads complete; safe to overwrite with s16
    if (t < 224) {
        #pragma unroll
        for (int wi = 0; wi < 14; ++wi)
            s16[(w0 + wi) * 58 + cj] = (f16)e[wi];
    }
    __syncthreads();

    // ---- Phase D: sv + sve via fdot2 over j-pairs. t<224: (w=t/4, cq=t%4) ----
    if (t < 224) {
        const int w = t >> 2, cq = t & 3;
        const f16* vp = vt2 + ((size_t)(b * GG + g) * NBLK * HH + w) * 32 + cq * 8;
        const f16* pb = &s16[w * 58];
        float sv[4] = {0.f, 0.f, 0.f, 0.f};
        float se[4] = {0.f, 0.f, 0.f, 0.f};
        #pragma unroll 2
        for (int J = 0; J < 28; J += 2) {
            const f16x4 pp4 = *(const f16x4*)(pb + 2 * J);   // p for J, J+1
            #pragma unroll
            for (int u = 0; u < 2; ++u) {
                const f16x2 pp = ((const f16x2*)&pp4)[u];
                const f16x8 vl = *(const f16x8*)(vp + (size_t)u * (HH * 32));
                const f16x8 el = *(const f16x8*)&ve2[(J + u) * 32 + cq * 8];
                #pragma unroll
                for (int c = 0; c < 4; ++c) {
                    sv[c] = __builtin_amdgcn_fdot2(pp, ((const f16x2*)&vl)[c], sv[c], false);
                    se[c] = __builtin_amdgcn_fdot2(pp, ((const f16x2*)&el)[c], se[c], false);
                }
            }
            vp += 2 * HH * 32;
        }
        const int ch = g * 16 + cq * 4;
        const float4 gsv  = *(const float4*)(g_sv + ch);
        const float4 bsv  = *(const float4*)(b_sv + ch);
        const float4 gsve = *(const float4*)(g_sve + ch);
        const float4 bsve = *(const float4*)(b_sve + ch);
        float4 o;
        o.x = fmaf(gsv.x * inv, sv[0], bsv.x) + fmaf(gsve.x * inv, se[0], bsve.x);
        o.y = fmaf(gsv.y * inv, sv[1], bsv.y) + fmaf(gsve.y * inv, se[1], bsve.y);
        o.z = fmaf(gsv.z * inv, sv[2], bsv.z) + fmaf(gsve.z * inv, se[2], bsve.z);
        o.w = fmaf(gsv.w * inv, sv[3], bsv.w) + fmaf(gsve.w * inv, se[3], bsve.w);
        *(float4*)(out + ((size_t)(b * HH + i) * HH + w) * 128 + ch) = o;
    }
}

// -------------------------------------------------------------------------
extern "C" void kernel_launch(void* const* d_in, const int* in_sizes, int n_in,
                              void* d_out, int out_size, void* d_ws, size_t ws_size,
                              hipStream_t stream)
{
    const float* x     = (const float*)d_in[0];
    const float* w_q   = (const float*)d_in[1];
    const float* w_k   = (const float*)d_in[2];
    const float* w_v   = (const float*)d_in[3];
    const float* q_rel = (const float*)d_in[4];
    const float* k_rel = (const float*)d_in[5];
    const float* v_rel = (const float*)d_in[6];
    const float* g_q   = (const float*)d_in[7];
    const float* b_q   = (const float*)d_in[8];
    const float* g_k   = (const float*)d_in[9];
    const float* b_k   = (const float*)d_in[10];
    const float* g_v   = (const float*)d_in[11];
    const float* b_v   = (const float*)d_in[12];
    const float* g_qk  = (const float*)d_in[13];
    const float* b_qk  = (const float*)d_in[14];
    const float* g_qr  = (const float*)d_in[15];
    const float* b_qr  = (const float*)d_in[16];
    const float* g_kr  = (const float*)d_in[17];
    const float* b_kr  = (const float*)d_in[18];
    const float* g_sv  = (const float*)d_in[19];
    const float* b_sv  = (const float*)d_in[20];
    const float* g_sve = (const float*)d_in[21];
    const float* b_sve = (const float*)d_in[22];
    float* out = (float*)d_out;

    // workspace (f16): wt 32768 | qt/kt 6,422,528 each | vt2 12,845,056 (~51.5 MB)
    f16* wt  = (f16*)d_ws;
    f16* qt  = wt + 32768;
    f16* kt  = qt + (size_t)NB * GG * PLANE * 8;
    f16* vt2 = kt + (size_t)NB * GG * PLANE * 8;

    prep_kernel<<<16, 256, 0, stream>>>(w_q, w_k, w_v, wt);

    qkv_kernel<<<dim3((NB * PLANE) / MT, 2), 256, 0, stream>>>(
        x, wt, g_q, b_q, g_k, b_k, g_v, b_v, qt, kt, vt2);

    attn_kernel<<<dim3(56, 8, 32), 256, 0, stream>>>(
        qt, kt, vt2, q_rel, k_rel, v_rel,
        g_qk, b_qk, g_qr, b_qr, g_kr, b_kr, g_sv, b_sv, g_sve, b_sve, out);
}